// Round 1
// baseline (301.952 us; speedup 1.0000x reference)
//
#include <hip/hip_runtime.h>

#define BB 64
#define SS 512
#define DD 768
#define NROWS (BB*SS)   // 32768

// ---------------------------------------------------------------------------
// Kernel 1: masked emissions em = relu((mask? seq·W^T : 0) + b), T=2.
// One wave per row. Writes em in time-major (s,b,t) layout for kernel 2,
// tags_t (s,b), and the labels_m / mask outputs directly.
// ---------------------------------------------------------------------------
__global__ __launch_bounds__(256) void k_emissions(
    const float* __restrict__ seq,      // (B*S, 768)
    const int*   __restrict__ input_ids,// (B*S)
    const int*   __restrict__ labels,   // (B*S)
    const float* __restrict__ W,        // (2,768)
    const float* __restrict__ bias,     // (2)
    float* __restrict__ em_t,           // ws: (S, B, 2)
    int*   __restrict__ tags_t,         // ws: (S, B)
    float* __restrict__ out)            // full output buffer
{
    const int lane  = threadIdx.x & 63;
    const int wid   = blockIdx.x * (blockDim.x >> 6) + (threadIdx.x >> 6);
    const int nwav  = gridDim.x * (blockDim.x >> 6);

    // W chunks for this lane, in registers (reused across rows).
    const float4* W4 = (const float4*)W;
    float4 w0[3], w1[3];
#pragma unroll
    for (int j = 0; j < 3; ++j) {
        w0[j] = W4[j*64 + lane];          // row 0: float4 idx 0..191
        w1[j] = W4[192 + j*64 + lane];    // row 1: float4 idx 192..383
    }
    const float b0 = bias[0], b1 = bias[1];

    for (int row = wid; row < NROWS; row += nwav) {
        const float4* p = (const float4*)(seq + (size_t)row * DD);
        float d0 = 0.f, d1 = 0.f;
#pragma unroll
        for (int j = 0; j < 3; ++j) {
            float4 v = p[j*64 + lane];    // coalesced: 1 KB per wave-instruction
            d0 += v.x*w0[j].x + v.y*w0[j].y + v.z*w0[j].z + v.w*w0[j].w;
            d1 += v.x*w1[j].x + v.y*w1[j].y + v.z*w1[j].z + v.w*w1[j].w;
        }
#pragma unroll
        for (int m = 32; m >= 1; m >>= 1) {
            d0 += __shfl_xor(d0, m, 64);
            d1 += __shfl_xor(d1, m, 64);
        }
        if (lane == 0) {
            const int id  = input_ids[row];
            const int lab = labels[row];
            const int msk = (id != 0 && id != 103 && lab != 100) ? 1 : 0;
            const int lm  = lab * msk;
            const float e0 = fmaxf((msk ? d0 : 0.f) + b0, 0.f);
            const float e1 = fmaxf((msk ? d1 : 0.f) + b1, 0.f);
            const int b_ = row >> 9;      // row = b*512 + s
            const int s_ = row & 511;
            em_t[(s_*BB + b_)*2 + 0] = e0;
            em_t[(s_*BB + b_)*2 + 1] = e1;
            tags_t[s_*BB + b_] = lm;
            out[1 + NROWS   + row] = (float)lm;   // labels_m
            out[1 + 2*NROWS + row] = (float)msk;  // mask
        }
    }
}

// ---------------------------------------------------------------------------
// Kernel 2: CRF. Wave 0 = forward logsumexp + gold score -> loss.
//           Wave 1 = Viterbi with bit-packed backpointers -> tags.
// One lane per sequence (64 sequences). Single block.
// ---------------------------------------------------------------------------
__device__ __forceinline__ float lse2(float x, float y) {
    float m = fmaxf(x, y);
    float d = fminf(x, y) - m;               // <= 0
    return m + __logf(1.f + __expf(d));
}

__global__ __launch_bounds__(128) void k_crf(
    const float* __restrict__ em_t,   // (S,B,2)
    const int*   __restrict__ tags_t, // (S,B)
    const float* __restrict__ start,
    const float* __restrict__ endt,
    const float* __restrict__ trans,  // (2,2) row-major
    float* __restrict__ out)
{
    __shared__ unsigned char tags_sh[NROWS];    // 32 KB: tags in (b,s) order
    __shared__ unsigned int  bp_words[BB*32];   // 8 KB: 2 bits/step, 16 steps/word
    const int tid = threadIdx.x;
    const float t00 = trans[0], t01 = trans[1], t10 = trans[2], t11 = trans[3];
    const float s0 = start[0], s1 = start[1];
    const float e0 = endt[0],  e1 = endt[1];

    if (tid < 64) {
        // ---- log-likelihood for sequence b = tid ----
        const int b = tid;
        float em0 = em_t[b*2 + 0];
        float em1 = em_t[b*2 + 1];
        int   tag = tags_t[b];
        float a0 = s0 + em0, a1 = s1 + em1;
        float score = tag ? (s1 + em1) : (s0 + em0);
        int ptag = tag;
        for (int k = 1; k < SS; ++k) {
            em0 = em_t[(k*BB + b)*2 + 0];
            em1 = em_t[(k*BB + b)*2 + 1];
            tag = tags_t[k*BB + b];
            float n0 = lse2(a0 + t00, a1 + t10) + em0;
            float n1 = lse2(a0 + t01, a1 + t11) + em1;
            a0 = n0; a1 = n1;
            float tr = ptag ? (tag ? t11 : t10) : (tag ? t01 : t00);
            score += tr + (tag ? em1 : em0);
            ptag = tag;
        }
        score += ptag ? e1 : e0;
        float logZ = lse2(a0 + e0, a1 + e1);
        float llh = score - logZ;
#pragma unroll
        for (int m = 32; m >= 1; m >>= 1) llh += __shfl_xor(llh, m, 64);
        if (tid == 0) out[0] = llh / (float)NROWS;
    } else {
        // ---- Viterbi for sequence b = tid - 64 ----
        const int b = tid - 64;
        float em0 = em_t[b*2 + 0];
        float em1 = em_t[b*2 + 1];
        float v0 = s0 + em0, v1 = s1 + em1;
        unsigned int acc = 0;
        for (int k = 1; k < SS; ++k) {
            em0 = em_t[(k*BB + b)*2 + 0];
            em1 = em_t[(k*BB + b)*2 + 1];
            float c00 = v0 + t00, c10 = v1 + t10;
            float c01 = v0 + t01, c11 = v1 + t11;
            int bp0 = (c10 > c00);            // jnp argmax: first occurrence on tie
            int bp1 = (c11 > c01);
            v0 = fmaxf(c00, c10) + em0;
            v1 = fmaxf(c01, c11) + em1;
            acc |= (unsigned)(bp0 | (bp1 << 1)) << (2*(k & 15));
            if ((k & 15) == 15) { bp_words[b*32 + (k >> 4)] = acc; acc = 0; }
        }
        float f0 = v0 + e0, f1 = v1 + e1;
        int tag = (f1 > f0);
        tags_sh[b*SS + (SS-1)] = (unsigned char)tag;
        for (int k = SS-1; k >= 1; --k) {
            unsigned int word = bp_words[b*32 + (k >> 4)];  // addr indep. of tag -> pipelined
            int bits = (word >> (2*(k & 15))) & 3;
            int prev = (bits >> tag) & 1;
            tags_sh[b*SS + (k-1)] = (unsigned char)prev;
            tag = prev;
        }
    }
    __syncthreads();
    // Coalesced float writeout of tags (target_emissions), (b,s) row-major.
    for (int idx = tid; idx < NROWS; idx += 128) {
        out[1 + idx] = (float)tags_sh[idx];
    }
}

extern "C" void kernel_launch(void* const* d_in, const int* in_sizes, int n_in,
                              void* d_out, int out_size, void* d_ws, size_t ws_size,
                              hipStream_t stream) {
    const float* seq    = (const float*)d_in[0];
    const int*   ids    = (const int*)  d_in[1];
    const int*   labels = (const int*)  d_in[2];
    const float* W      = (const float*)d_in[3];
    const float* bias   = (const float*)d_in[4];
    const float* start  = (const float*)d_in[5];
    const float* endt   = (const float*)d_in[6];
    const float* trans  = (const float*)d_in[7];
    float* out = (float*)d_out;

    float* em_t   = (float*)d_ws;                                  // 65536 floats (256 KB)
    int*   tags_t = (int*)((char*)d_ws + (size_t)65536*sizeof(float)); // 32768 ints (128 KB)

    k_emissions<<<2048, 256, 0, stream>>>(seq, ids, labels, W, bias, em_t, tags_t, out);
    k_crf<<<1, 128, 0, stream>>>(em_t, tags_t, start, endt, trans, out);
}

// Round 2
// 198.180 us; speedup vs baseline: 1.5236x; 1.5236x over previous
//
#include <hip/hip_runtime.h>

#define BB 64
#define SS 512
#define DD 768
#define NROWS (BB*SS)   // 32768
#define NEG (-1e30f)

// ---------------------------------------------------------------------------
// Kernel 1: masked emissions em = relu((mask? seq.W^T : 0) + b), T=2.
// One wave per 4 rows: 12 independent float4 loads in flight, 8 interleaved
// butterfly reduction chains. Writes em in time-major (s,b,2), tags (s,b),
// and the labels_m / mask outputs.
// ---------------------------------------------------------------------------
__global__ __launch_bounds__(256) void k_emissions(
    const float* __restrict__ seq,      // (B*S, 768)
    const int*   __restrict__ input_ids,
    const int*   __restrict__ labels,
    const float* __restrict__ W,        // (2,768)
    const float* __restrict__ bias,     // (2)
    float* __restrict__ em_t,           // ws: (S, B, 2)
    int*   __restrict__ tags_t,         // ws: (S, B)
    float* __restrict__ out)
{
    const int lane = threadIdx.x & 63;
    const int wid  = blockIdx.x * 4 + (threadIdx.x >> 6);
    const int base = wid * 4;           // 4 consecutive rows per wave

    const float4* W4 = (const float4*)W;
    float4 w0[3], w1[3];
#pragma unroll
    for (int j = 0; j < 3; ++j) {
        w0[j] = W4[j*64 + lane];
        w1[j] = W4[192 + j*64 + lane];
    }
    const float b0 = bias[0], b1 = bias[1];

    const float4* s4 = (const float4*)seq;
    float4 v[4][3];
#pragma unroll
    for (int r = 0; r < 4; ++r)
#pragma unroll
        for (int j = 0; j < 3; ++j)
            v[r][j] = s4[(size_t)(base + r)*192 + j*64 + lane];

    float d0[4], d1[4];
#pragma unroll
    for (int r = 0; r < 4; ++r) {
        float a0 = 0.f, a1 = 0.f;
#pragma unroll
        for (int j = 0; j < 3; ++j) {
            float4 x = v[r][j];
            a0 += x.x*w0[j].x + x.y*w0[j].y + x.z*w0[j].z + x.w*w0[j].w;
            a1 += x.x*w1[j].x + x.y*w1[j].y + x.z*w1[j].z + x.w*w1[j].w;
        }
        d0[r] = a0; d1[r] = a1;
    }
    // 8 interleaved butterfly chains
#pragma unroll
    for (int m = 32; m >= 1; m >>= 1) {
#pragma unroll
        for (int r = 0; r < 4; ++r) {
            d0[r] += __shfl_xor(d0[r], m, 64);
            d1[r] += __shfl_xor(d1[r], m, 64);
        }
    }
    if (lane == 0) {
        const int4 idv = *(const int4*)(input_ids + base);
        const int4 lbv = *(const int4*)(labels + base);
        const int ida[4] = {idv.x, idv.y, idv.z, idv.w};
        const int lba[4] = {lbv.x, lbv.y, lbv.z, lbv.w};
#pragma unroll
        for (int r = 0; r < 4; ++r) {
            const int row = base + r;
            const int id = ida[r], lab = lba[r];
            const int msk = (id != 0 && id != 103 && lab != 100) ? 1 : 0;
            const int lm  = lab * msk;
            const float e0 = fmaxf((msk ? d0[r] : 0.f) + b0, 0.f);
            const float e1 = fmaxf((msk ? d1[r] : 0.f) + b1, 0.f);
            const int b_ = row >> 9, s_ = row & 511;
            *(float2*)(em_t + (s_*BB + b_)*2) = make_float2(e0, e1);
            tags_t[s_*BB + b_] = lm;
            out[1 + NROWS   + row] = (float)lm;
            out[1 + 2*NROWS + row] = (float)msk;
        }
    }
}

// ---------------------------------------------------------------------------
// Kernel 2: CRF via chunked semiring scans. 1 block x 512 threads.
//  phase1: wave c computes 64-step chunk products: log-semiring (logZ),
//          max-plus (Viterbi), + gold-score partial. Depth-21 prefetch.
//  phase2: wave0 combines logZ+score -> loss; wave1 combines Viterbi ->
//          chunk-boundary states + final tag.
//  phase3: wave c recomputes chunk forward storing bit-packed backpointers.
//  phase4: wave0 backtracks (padded LDS -> no bank conflicts).
//  phase5: all threads write tags as float.
// ---------------------------------------------------------------------------
__device__ __forceinline__ float lse2(float x, float y) {
    float m = fmaxf(x, y);
    float d = fminf(x, y) - m;
    return m + __logf(1.f + __expf(d));
}

__global__ __launch_bounds__(512) void k_crf(
    const float* __restrict__ em_t,   // (S,B,2)
    const int*   __restrict__ tags_t, // (S,B)
    const float* __restrict__ start,
    const float* __restrict__ endt,
    const float* __restrict__ trans,
    float* __restrict__ out)
{
    __shared__ float4 logP4[8][64];          // 8 KB chunk log-semiring mats
    __shared__ float4 vitP4[8][64];          // 8 KB chunk max-plus mats
    __shared__ float  scoreP[8][64];         // 2 KB gold-score partials
    __shared__ float2 vbound[8][64];         // 4 KB viterbi chunk-entry states
    __shared__ unsigned char last_tag_sh[64];
    __shared__ unsigned int  bp_sh[64*33];   // padded: 33 words per seq
    __shared__ unsigned char tags_sh[64*516];// padded stride 516

    const int tid  = threadIdx.x;
    const int lane = tid & 63;
    const int wv   = tid >> 6;               // 0..7 = chunk id
    const float t00 = trans[0], t01 = trans[1], t10 = trans[2], t11 = trans[3];
    const float s0 = start[0], s1 = start[1];
    const float e0 = endt[0],  e1 = endt[1];
    const float2* em2 = (const float2*)em_t;

    // ---------------- phase 1 ----------------
    {
        const int b = lane, c = wv;
        const int k0 = c * 64;
        float2 emv = em2[k0*64 + b];
        int    tg  = tags_t[k0*64 + b];
        float P00,P01,P10,P11, V00,V01,V10,V11, score;
        if (c == 0) {
            P00 = 0.f; P01 = NEG; P10 = NEG; P11 = 0.f;
            V00 = 0.f; V01 = NEG; V10 = NEG; V11 = 0.f;
            score = tg ? (s1 + emv.y) : (s0 + emv.x);
        } else {
            int pt = tags_t[(k0-1)*64 + b];
            P00 = t00 + emv.x; P01 = t01 + emv.y;
            P10 = t10 + emv.x; P11 = t11 + emv.y;
            V00 = P00; V01 = P01; V10 = P10; V11 = P11;
            score = (pt ? (tg ? t11 : t10) : (tg ? t01 : t00))
                  + (tg ? emv.y : emv.x);
        }
        int ptag = tg;

        // pipelined 63 steps: k = k0+1 .. k0+63, prefetch depth 21
        float2 eb[21]; int tb[21];
#pragma unroll
        for (int i = 0; i < 21; ++i) {
            int kp = k0 + 1 + i;
            eb[i] = em2[kp*64 + b];
            tb[i] = tags_t[kp*64 + b];
        }
#pragma unroll
        for (int jb = 0; jb < 3; ++jb) {
#pragma unroll
            for (int i = 0; i < 21; ++i) {
                const int k = k0 + 1 + jb*21 + i;
                float2 em = eb[i]; int tag = tb[i];
                int kp = k + 21; if (kp > 511) kp = 511;
                eb[i] = em2[kp*64 + b];
                tb[i] = tags_t[kp*64 + b];

                float x0 = lse2(P00 + t00, P01 + t10) + em.x;
                float x1 = lse2(P00 + t01, P01 + t11) + em.y;
                float x2 = lse2(P10 + t00, P11 + t10) + em.x;
                float x3 = lse2(P10 + t01, P11 + t11) + em.y;
                P00 = x0; P01 = x1; P10 = x2; P11 = x3;

                float m0 = fmaxf(V00 + t00, V01 + t10) + em.x;
                float m1 = fmaxf(V00 + t01, V01 + t11) + em.y;
                float m2 = fmaxf(V10 + t00, V11 + t10) + em.x;
                float m3 = fmaxf(V10 + t01, V11 + t11) + em.y;
                V00 = m0; V01 = m1; V10 = m2; V11 = m3;

                score += (ptag ? (tag ? t11 : t10) : (tag ? t01 : t00))
                       + (tag ? em.y : em.x);
                ptag = tag;
            }
        }
        logP4[c][b] = make_float4(P00, P01, P10, P11);
        vitP4[c][b] = make_float4(V00, V01, V10, V11);
        scoreP[c][b] = score;
    }
    __syncthreads();

    // ---------------- phase 2 ----------------
    if (wv == 0) {
        const int b = lane;
        float2 em0v = em2[b];
        float a0 = s0 + em0v.x, a1 = s1 + em0v.y;
        float sc = 0.f;
#pragma unroll
        for (int c = 0; c < 8; ++c) {
            float4 P = logP4[c][b];
            float n0 = lse2(a0 + P.x, a1 + P.z);
            float n1 = lse2(a0 + P.y, a1 + P.w);
            a0 = n0; a1 = n1;
            sc += scoreP[c][b];
        }
        int tagL = tags_t[511*64 + b];
        sc += tagL ? e1 : e0;
        float logZ = lse2(a0 + e0, a1 + e1);
        float llh = sc - logZ;
#pragma unroll
        for (int m = 32; m >= 1; m >>= 1) llh += __shfl_xor(llh, m, 64);
        if (lane == 0) out[0] = llh / (float)NROWS;
    } else if (wv == 1) {
        const int b = lane;
        float2 em0v = em2[b];
        float v0 = s0 + em0v.x, v1 = s1 + em0v.y;
        vbound[0][b] = make_float2(v0, v1);
#pragma unroll
        for (int c = 0; c < 8; ++c) {
            float4 V = vitP4[c][b];
            float n0 = fmaxf(v0 + V.x, v1 + V.z);
            float n1 = fmaxf(v0 + V.y, v1 + V.w);
            v0 = n0; v1 = n1;
            if (c < 7) vbound[c+1][b] = make_float2(v0, v1);
        }
        int last = (v1 + e1 > v0 + e0) ? 1 : 0;
        last_tag_sh[b] = (unsigned char)last;
        tags_sh[b*516 + 511] = (unsigned char)last;
    }
    __syncthreads();

    // ---------------- phase 3: backpointers ----------------
    {
        const int b = lane, c = wv;
        const int k0 = c * 64;
        float2 vb = vbound[c][b];
        float v0 = vb.x, v1 = vb.y;
        unsigned int acc = 0;

        float2 eb[16];
#pragma unroll
        for (int i = 0; i < 16; ++i) eb[i] = em2[(k0 + i)*64 + b];
#pragma unroll
        for (int jb = 0; jb < 4; ++jb) {
#pragma unroll
            for (int i = 0; i < 16; ++i) {
                const int k = k0 + jb*16 + i;
                float2 em = eb[i];
                int kp = k + 16; if (kp > 511) kp = 511;
                eb[i] = em2[kp*64 + b];
                if (k > 0) {
                    float c00 = v0 + t00, c10 = v1 + t10;
                    float c01 = v0 + t01, c11 = v1 + t11;
                    int bp0 = (c10 > c00);
                    int bp1 = (c11 > c01);
                    v0 = fmaxf(c00, c10) + em.x;
                    v1 = fmaxf(c01, c11) + em.y;
                    acc |= (unsigned)(bp0 | (bp1 << 1)) << (2*(k & 15));
                }
                if ((k & 15) == 15) { bp_sh[b*33 + (k >> 4)] = acc; acc = 0; }
            }
        }
    }
    __syncthreads();

    // ---------------- phase 4: backtrack ----------------
    if (wv == 0) {
        const int b = lane;
        int tag = last_tag_sh[b];
        for (int w = 31; w >= 0; --w) {
            unsigned int word = bp_sh[b*33 + w];
#pragma unroll
            for (int i = 15; i >= 0; --i) {
                const int k = w*16 + i;
                if (k >= 1) {
                    int prev = (word >> ((2*i) | tag)) & 1;
                    tags_sh[b*516 + (k-1)] = (unsigned char)prev;
                    tag = prev;
                }
            }
        }
    }
    __syncthreads();

    // ---------------- phase 5: writeout ----------------
    for (int idx = tid; idx < NROWS; idx += 512) {
        out[1 + idx] = (float)tags_sh[(idx >> 9)*516 + (idx & 511)];
    }
}

extern "C" void kernel_launch(void* const* d_in, const int* in_sizes, int n_in,
                              void* d_out, int out_size, void* d_ws, size_t ws_size,
                              hipStream_t stream) {
    const float* seq    = (const float*)d_in[0];
    const int*   ids    = (const int*)  d_in[1];
    const int*   labels = (const int*)  d_in[2];
    const float* W      = (const float*)d_in[3];
    const float* bias   = (const float*)d_in[4];
    const float* start  = (const float*)d_in[5];
    const float* endt   = (const float*)d_in[6];
    const float* trans  = (const float*)d_in[7];
    float* out = (float*)d_out;

    float* em_t   = (float*)d_ws;                                      // 256 KB
    int*   tags_t = (int*)((char*)d_ws + (size_t)65536*sizeof(float)); // 128 KB

    k_emissions<<<2048, 256, 0, stream>>>(seq, ids, labels, W, bias, em_t, tags_t, out);
    k_crf<<<1, 512, 0, stream>>>(em_t, tags_t, start, endt, trans, out);
}

// Round 3
// 183.080 us; speedup vs baseline: 1.6493x; 1.0825x over previous
//
#include <hip/hip_runtime.h>

#define BB 64
#define SS 512
#define DD 768
#define NROWS (BB*SS)   // 32768
#define NEG (-1e30f)
#define NCH 16          // chunks per sequence
#define CL  32          // chunk length (NCH*CL == SS)

// ---------------------------------------------------------------------------
// Kernel 1: masked emissions em = relu((mask? seq.W^T : 0) + b), T=2.
// One wave per 4 rows. Writes em time-major (s,b,2), tags (s,b), labels_m/mask.
// ---------------------------------------------------------------------------
__global__ __launch_bounds__(256) void k_emissions(
    const float* __restrict__ seq,
    const int*   __restrict__ input_ids,
    const int*   __restrict__ labels,
    const float* __restrict__ W,
    const float* __restrict__ bias,
    float* __restrict__ em_t,           // ws: (S, B, 2)
    int*   __restrict__ tags_t,         // ws: (S, B)
    float* __restrict__ out)
{
    const int lane = threadIdx.x & 63;
    const int wid  = blockIdx.x * 4 + (threadIdx.x >> 6);
    const int base = wid * 4;

    const float4* W4 = (const float4*)W;
    float4 w0[3], w1[3];
#pragma unroll
    for (int j = 0; j < 3; ++j) {
        w0[j] = W4[j*64 + lane];
        w1[j] = W4[192 + j*64 + lane];
    }
    const float b0 = bias[0], b1 = bias[1];

    const float4* s4 = (const float4*)seq;
    float4 v[4][3];
#pragma unroll
    for (int r = 0; r < 4; ++r)
#pragma unroll
        for (int j = 0; j < 3; ++j)
            v[r][j] = s4[(size_t)(base + r)*192 + j*64 + lane];

    float d0[4], d1[4];
#pragma unroll
    for (int r = 0; r < 4; ++r) {
        float a0 = 0.f, a1 = 0.f;
#pragma unroll
        for (int j = 0; j < 3; ++j) {
            float4 x = v[r][j];
            a0 += x.x*w0[j].x + x.y*w0[j].y + x.z*w0[j].z + x.w*w0[j].w;
            a1 += x.x*w1[j].x + x.y*w1[j].y + x.z*w1[j].z + x.w*w1[j].w;
        }
        d0[r] = a0; d1[r] = a1;
    }
#pragma unroll
    for (int m = 32; m >= 1; m >>= 1) {
#pragma unroll
        for (int r = 0; r < 4; ++r) {
            d0[r] += __shfl_xor(d0[r], m, 64);
            d1[r] += __shfl_xor(d1[r], m, 64);
        }
    }
    if (lane == 0) {
        const int4 idv = *(const int4*)(input_ids + base);
        const int4 lbv = *(const int4*)(labels + base);
        const int ida[4] = {idv.x, idv.y, idv.z, idv.w};
        const int lba[4] = {lbv.x, lbv.y, lbv.z, lbv.w};
#pragma unroll
        for (int r = 0; r < 4; ++r) {
            const int row = base + r;
            const int id = ida[r], lab = lba[r];
            const int msk = (id != 0 && id != 103 && lab != 100) ? 1 : 0;
            const int lm  = lab * msk;
            const float e0 = fmaxf((msk ? d0[r] : 0.f) + b0, 0.f);
            const float e1 = fmaxf((msk ? d1[r] : 0.f) + b1, 0.f);
            const int b_ = row >> 9, s_ = row & 511;
            *(float2*)(em_t + (s_*BB + b_)*2) = make_float2(e0, e1);
            tags_t[s_*BB + b_] = lm;
            out[1 + NROWS   + row] = (float)lm;
            out[1 + 2*NROWS + row] = (float)msk;
        }
    }
}

// ---------------------------------------------------------------------------
// Kernel 2: CRF, grid = 2 blocks x 1024 threads.
//   block 0: loss (log-semiring chunk products + gold score -> llh)
//   block 1: viterbi (max-plus chunk products -> boundary states ->
//            backpointers -> backtrack -> bit-packed tags -> writeout)
// wave = chunk (16 chunks of 32 steps), lane = sequence.
// ---------------------------------------------------------------------------
__device__ __forceinline__ float lse2(float x, float y) {
    float m = fmaxf(x, y);
    float d = fminf(x, y) - m;
    return m + __logf(1.f + __expf(d));
}

#define STEP_L(e_, g_) do { \
    float n0 = lse2(P00 + t00, P01 + t10) + (e_).x; \
    float n1 = lse2(P00 + t01, P01 + t11) + (e_).y; \
    float n2 = lse2(P10 + t00, P11 + t10) + (e_).x; \
    float n3 = lse2(P10 + t01, P11 + t11) + (e_).y; \
    P00 = n0; P01 = n1; P10 = n2; P11 = n3; \
    score += (ptag ? ((g_) ? t11 : t10) : ((g_) ? t01 : t00)) \
           + ((g_) ? (e_).y : (e_).x); \
    ptag = (g_); \
} while (0)

#define STEP_VP(e_) do { \
    float n0 = fmaxf(V00 + t00, V01 + t10) + (e_).x; \
    float n1 = fmaxf(V00 + t01, V01 + t11) + (e_).y; \
    float n2 = fmaxf(V10 + t00, V11 + t10) + (e_).x; \
    float n3 = fmaxf(V10 + t01, V11 + t11) + (e_).y; \
    V00 = n0; V01 = n1; V10 = n2; V11 = n3; \
} while (0)

#define STEP_BP(k_, e_) do { \
    float c00 = v0 + t00, c10 = v1 + t10; \
    float c01 = v0 + t01, c11 = v1 + t11; \
    int bp0 = (c10 > c00); int bp1 = (c11 > c01); \
    v0 = fmaxf(c00, c10) + (e_).x; v1 = fmaxf(c01, c11) + (e_).y; \
    acc |= (unsigned)(bp0 | (bp1 << 1)) << (2 * ((k_) & 15)); \
    if ((((k_) & 15)) == 15) { bp_sh[b*33 + ((k_) >> 4)] = acc; acc = 0u; } \
} while (0)

__global__ __launch_bounds__(1024) void k_crf(
    const float* __restrict__ em_t,   // (S,B,2)
    const int*   __restrict__ tags_t, // (S,B)
    const float* __restrict__ start,
    const float* __restrict__ endt,
    const float* __restrict__ trans,
    float* __restrict__ out)
{
    __shared__ float4 logP4[NCH][BB];     // 16 KB
    __shared__ float  scoreP[NCH][BB];    //  4 KB
    __shared__ float4 vitP4[NCH][BB];     // 16 KB
    __shared__ float2 vbound[NCH][BB];    //  8 KB
    __shared__ unsigned int bp_sh[BB*33]; //  8.25 KB (padded)
    __shared__ unsigned int tagbits[BB*17]; // 4.25 KB (padded)

    const int tid = threadIdx.x;
    const int b   = tid & 63;     // sequence
    const int c   = tid >> 6;     // chunk / wave id
    const int k0  = c * CL;
    const float t00 = trans[0], t01 = trans[1], t10 = trans[2], t11 = trans[3];
    const float s0 = start[0], s1 = start[1];
    const float en0 = endt[0], en1 = endt[1];
    const float2* em2 = (const float2*)em_t;

    if (blockIdx.x == 0) {
        // ================= LOSS =================
        float2 e[8]; int g[8];
        float P00, P01, P10, P11, score; int ptag;
#pragma unroll
        for (int i = 0; i < 8; ++i) {
            e[i] = em2[(k0+i)*BB + b];
            g[i] = tags_t[(k0+i)*BB + b];
        }
        if (c == 0) {
            P00 = 0.f; P01 = NEG; P10 = NEG; P11 = 0.f;
            score = g[0] ? (s1 + e[0].y) : (s0 + e[0].x);
        } else {
            int pt = tags_t[(k0-1)*BB + b];
            P00 = t00 + e[0].x; P01 = t01 + e[0].y;
            P10 = t10 + e[0].x; P11 = t11 + e[0].y;
            score = (pt ? (g[0] ? t11 : t10) : (g[0] ? t01 : t00))
                  + (g[0] ? e[0].y : e[0].x);
        }
        ptag = g[0];
#pragma unroll
        for (int i = 1; i < 8; ++i) STEP_L(e[i], g[i]);
#pragma unroll
        for (int j = 1; j < 4; ++j) {
#pragma unroll
            for (int i = 0; i < 8; ++i) {
                e[i] = em2[(k0 + j*8 + i)*BB + b];
                g[i] = tags_t[(k0 + j*8 + i)*BB + b];
            }
#pragma unroll
            for (int i = 0; i < 8; ++i) STEP_L(e[i], g[i]);
        }
        logP4[c][b] = make_float4(P00, P01, P10, P11);
        scoreP[c][b] = score;
        __syncthreads();
        if (c == 0) {
            float2 em0v = em2[b];
            float a0 = s0 + em0v.x, a1 = s1 + em0v.y, sc = 0.f;
#pragma unroll
            for (int cc = 0; cc < NCH; ++cc) {
                float4 P = logP4[cc][b];
                float n0 = lse2(a0 + P.x, a1 + P.z);
                float n1 = lse2(a0 + P.y, a1 + P.w);
                a0 = n0; a1 = n1;
                sc += scoreP[cc][b];
            }
            int tagL = tags_t[511*BB + b];
            sc += tagL ? en1 : en0;
            float logZ = lse2(a0 + en0, a1 + en1);
            float llh = sc - logZ;
#pragma unroll
            for (int m = 32; m >= 1; m >>= 1) llh += __shfl_xor(llh, m, 64);
            if (b == 0) out[0] = llh / (float)NROWS;
        }
    } else {
        // ================= VITERBI =================
        float2 e[8];
        float V00, V01, V10, V11;
#pragma unroll
        for (int i = 0; i < 8; ++i) e[i] = em2[(k0+i)*BB + b];
        if (c == 0) {
            V00 = 0.f; V01 = NEG; V10 = NEG; V11 = 0.f;
        } else {
            V00 = t00 + e[0].x; V01 = t01 + e[0].y;
            V10 = t10 + e[0].x; V11 = t11 + e[0].y;
        }
#pragma unroll
        for (int i = 1; i < 8; ++i) STEP_VP(e[i]);
#pragma unroll
        for (int j = 1; j < 4; ++j) {
#pragma unroll
            for (int i = 0; i < 8; ++i) e[i] = em2[(k0 + j*8 + i)*BB + b];
#pragma unroll
            for (int i = 0; i < 8; ++i) STEP_VP(e[i]);
        }
        vitP4[c][b] = make_float4(V00, V01, V10, V11);
        __syncthreads();

        int last = 0;
        if (c == 0) {
            float2 em0v = em2[b];
            float v0 = s0 + em0v.x, v1 = s1 + em0v.y;
            vbound[0][b] = make_float2(v0, v1);
#pragma unroll
            for (int cc = 0; cc < NCH; ++cc) {
                float4 V = vitP4[cc][b];
                float n0 = fmaxf(v0 + V.x, v1 + V.z);
                float n1 = fmaxf(v0 + V.y, v1 + V.w);
                v0 = n0; v1 = n1;
                if (cc < NCH-1) vbound[cc+1][b] = make_float2(v0, v1);
            }
            last = (v1 + en1 > v0 + en0) ? 1 : 0;
        }
        __syncthreads();

        // phase 3: backpointer recompute (em re-read is L2-warm)
        {
            float2 vb = vbound[c][b];
            float v0 = vb.x, v1 = vb.y;
            unsigned acc = 0u;
#pragma unroll
            for (int i = 0; i < 8; ++i) e[i] = em2[(k0+i)*BB + b];
            if (c != 0) STEP_BP(k0, e[0]);
#pragma unroll
            for (int i = 1; i < 8; ++i) STEP_BP(k0 + i, e[i]);
#pragma unroll
            for (int j = 1; j < 4; ++j) {
#pragma unroll
                for (int i = 0; i < 8; ++i) e[i] = em2[(k0 + j*8 + i)*BB + b];
#pragma unroll
                for (int i = 0; i < 8; ++i) STEP_BP(k0 + j*8 + i, e[i]);
            }
        }
        __syncthreads();

        // phase 4: backtrack, bit-packed tags into LDS
        if (c == 0) {
            int tag = last;
            unsigned acc = ((unsigned)tag) << 31;     // position 511
            for (int w = 31; w >= 0; --w) {
                unsigned word = bp_sh[b*33 + w];
                const int kbase = w * 16;
#pragma unroll
                for (int i = 15; i >= 0; --i) {
                    if (kbase + i == 0) continue;     // k==0 has no predecessor
                    int prev = (word >> (2*i + tag)) & 1;
                    int pos = kbase + i - 1;
                    acc |= (unsigned)prev << (pos & 31);
                    if ((pos & 31) == 0) { tagbits[b*17 + (pos >> 5)] = acc; acc = 0u; }
                    tag = prev;
                }
            }
        }
        __syncthreads();

        // phase 5: coalesced float writeout of tags
        for (int idx = tid; idx < NROWS; idx += 1024) {
            const int bq = idx >> 9, k = idx & 511;
            unsigned wd = tagbits[bq*17 + (k >> 5)];
            out[1 + idx] = (float)((wd >> (k & 31)) & 1);
        }
    }
}

extern "C" void kernel_launch(void* const* d_in, const int* in_sizes, int n_in,
                              void* d_out, int out_size, void* d_ws, size_t ws_size,
                              hipStream_t stream) {
    const float* seq    = (const float*)d_in[0];
    const int*   ids    = (const int*)  d_in[1];
    const int*   labels = (const int*)  d_in[2];
    const float* W      = (const float*)d_in[3];
    const float* bias   = (const float*)d_in[4];
    const float* start  = (const float*)d_in[5];
    const float* endt   = (const float*)d_in[6];
    const float* trans  = (const float*)d_in[7];
    float* out = (float*)d_out;

    float* em_t   = (float*)d_ws;                                      // 256 KB
    int*   tags_t = (int*)((char*)d_ws + (size_t)65536*sizeof(float)); // 128 KB

    k_emissions<<<2048, 256, 0, stream>>>(seq, ids, labels, W, bias, em_t, tags_t, out);
    k_crf<<<2, 1024, 0, stream>>>(em_t, tags_t, start, endt, trans, out);
}